// Round 7
// baseline (173.006 us; speedup 1.0000x reference)
//
#include <hip/hip_runtime.h>

// VQ-VAE vector quantizer: B=32,C=64,H=64,W=64, K=512, DECAY=0.99, EPS=1e-5
// N = 131072 vectors, dim 64.
// R7: (1) argmin at 32 waves/CU, codebook streamed from L2 (no LDS stage);
// (2) vq_out also emits bf16 xT[n][64] via LDS transpose; (3) segsum rebuilt as
// owner-wave scan: wave w owns codes k&15==w, accumulates in 32 VGPRs (zero LDS
// atomics), windows staged to LDS with register prefetch; 64 plain slabs.

typedef __attribute__((ext_vector_type(8))) short bf16x8;
typedef __attribute__((ext_vector_type(16))) float f32x16;

#define MFMA32 __builtin_amdgcn_mfma_f32_32x32x16_bf16

__device__ __forceinline__ unsigned short f2bf(float f) {
    unsigned u = __float_as_uint(f);
    return (unsigned short)((u + 0x7fffu + ((u >> 16) & 1u)) >> 16);
}
__device__ __forceinline__ float bf2f(unsigned short h) {
    return __uint_as_float(((unsigned)h) << 16);
}

// ---- prep: esq + split hi/lo fragment-major bf16 codebook ----
// unit u = cs*2+hh, c = (u>>1)*16 + (u&1)*8 + j
// cbF layout: [hi: (u*512+k)*16B for 64KB][lo: same, +64KB]
__global__ void __launch_bounds__(512)
vq_prep(const float* __restrict__ cb, float* __restrict__ esq, char* __restrict__ cbF) {
    __shared__ float tile[64 * 65];
    const int tid = threadIdx.x;
    const int k0  = blockIdx.x * 64;
    #pragma unroll
    for (int i = tid; i < 4096; i += 512)
        tile[(i >> 6) * 65 + (i & 63)] = cb[k0 * 64 + i];
    __syncthreads();
    const int u  = tid >> 6;
    const int kl = tid & 63;
    const float* row = tile + kl * 65;
    const int cbase = (u >> 1) * 16 + (u & 1) * 8;
    bf16x8 h8, l8;
    #pragma unroll
    for (int j = 0; j < 8; ++j) {
        float e = row[cbase + j];
        unsigned short hb = f2bf(e);
        float lo = e - bf2f(hb);
        h8[j] = (short)hb;
        l8[j] = (short)f2bf(lo);
    }
    const size_t idx = (size_t)(u * 512 + k0 + kl) * 16;
    *(bf16x8*)(cbF + idx)         = h8;
    *(bf16x8*)(cbF + 65536 + idx) = l8;
    if (u == 0) {
        float s = 0.f;
        #pragma unroll
        for (int c = 0; c < 64; ++c) { float v = row[c]; s = fmaf(v, v, s); }
        esq[k0 + kl] = s;
    }
}

// top-2 update; kq ascending -> strict < keeps first (numpy argmin semantics)
__device__ __forceinline__ void upd(float s, int kq, float& b1, int& q1, float& b2, int& q2) {
    bool t1 = s < b1;
    bool t2 = s < b2;
    float nb2 = t1 ? b1 : (t2 ? s : b2);
    int   nq2 = t1 ? q1 : (t2 ? kq : q2);
    b2 = nb2; q2 = nq2;
    b1 = t1 ? s : b1;
    q1 = t1 ? kq : q1;
}

// 256 thr (4 waves), grid 1024; 8 blocks/CU -> 32 waves/CU. A-frags from L2.
__global__ void __launch_bounds__(256, 8)
vq_argmin(const float* __restrict__ x, const char* __restrict__ cbF,
          const float* __restrict__ esqg, unsigned int* __restrict__ bkp) {
    __shared__ float esq[512];
    const int tid  = threadIdx.x;
    const int lane = tid & 63;
    const int wv   = tid >> 6;        // 0..3
    const int l31  = lane & 31;
    const int hh   = lane >> 5;

    esq[tid] = esqg[tid];
    esq[tid + 256] = esqg[tid + 256];

    // ---- this wave's 32 x's: B fragments (-2x, hi/lo) ----
    const int n  = (blockIdx.x * 4 + wv) * 32 + l31;
    const int bb = n >> 12, h = (n >> 6) & 63;
    const long gx = (long)bb * 262144 + (long)h * 64 + (n & 63);
    bf16x8 Bh[4], Bl[4];
    #pragma unroll
    for (int cs = 0; cs < 4; ++cs) {
        bf16x8 h8, l8;
        #pragma unroll
        for (int j = 0; j < 8; ++j) {
            float v  = x[gx + (long)(cs * 16 + hh * 8 + j) * 4096];
            float m2 = -2.f * v;
            unsigned short hb = f2bf(m2);
            float lo = m2 - bf2f(hb);
            h8[j] = (short)hb;
            l8[j] = (short)f2bf(lo);
        }
        Bh[cs] = h8; Bl[cs] = l8;
    }
    __syncthreads();

    // ---- K loop: 16 tiles x 32 codes; A streamed from global (L2-hot) ----
    float b1 = 3.4e38f, b2 = 3.4e38f;
    int   q1 = 0,        q2 = 0;
    const bf16x8* chi = (const bf16x8*)cbF;
    const bf16x8* clo = (const bf16x8*)(cbF + 65536);
    #pragma unroll 1
    for (int kt = 0; kt < 16; ++kt) {
        bf16x8 Ah[4], Al[4];
        #pragma unroll
        for (int cs = 0; cs < 4; ++cs) {
            const int fi = (cs * 2 + hh) * 512 + kt * 32 + l31;
            Ah[cs] = chi[fi];
            Al[cs] = clo[fi];
        }
        f32x16 acc = {};
        #pragma unroll
        for (int cs = 0; cs < 4; ++cs) {
            acc = MFMA32(Ah[cs], Bh[cs], acc, 0, 0, 0);
            acc = MFMA32(Al[cs], Bh[cs], acc, 0, 0, 0);
            acc = MFMA32(Ah[cs], Bl[cs], acc, 0, 0, 0);
        }
        #pragma unroll
        for (int g = 0; g < 4; ++g) {
            float4 e4 = *(const float4*)(esq + kt * 32 + 8 * g + 4 * hh);
            const float ev[4] = {e4.x, e4.y, e4.z, e4.w};
            #pragma unroll
            for (int r = 0; r < 4; ++r) {
                int kq = kt * 32 + 8 * g + r;          // hh-free (add 4*hh at merge)
                upd(ev[r] + acc[4 * g + r], kq, b1, q1, b2, q2);
            }
        }
    }

    // ---- merge hh halves (true k = kq + 4*hh), export top-2 packed ----
    {
        float mb1 = b1, mb2 = b2;
        int   mk1 = q1 + 4 * hh, mk2 = q2 + 4 * hh;
        float ob1 = __shfl_xor(mb1, 32, 64); int ok1 = __shfl_xor(mk1, 32, 64);
        float ob2 = __shfl_xor(mb2, 32, 64); int ok2 = __shfl_xor(mk2, 32, 64);
        bool t = (ob1 < mb1) || (ob1 == mb1 && ok1 < mk1);
        float w1 = t ? ob1 : mb1;  int wk1 = t ? ok1 : mk1;
        float l1 = t ? mb1 : ob1;  int lk1 = t ? mk1 : ok1;
        float w2c = t ? ob2 : mb2; int wk2c = t ? ok2 : mk2;
        bool t2 = (w2c < l1) || (w2c == l1 && wk2c < lk1);
        float w2 = t2 ? w2c : l1;  int wk2 = t2 ? wk2c : lk1;
        if (hh == 0) {
            unsigned k2s = (w2 - w1 < 2e-3f) ? (unsigned)wk2 : (unsigned)wk1;
            bkp[n] = (unsigned)wk1 | (k2s << 16);
        }
    }
}

// ---- refine + out(=q) + loss + counts + bf16 xT emission (LDS transpose) ----
__global__ void __launch_bounds__(256)
vq_out(const float* __restrict__ x, const float* __restrict__ cbg,
       const float* __restrict__ esqg, const unsigned int* __restrict__ bkp,
       unsigned short* __restrict__ bkg, float* __restrict__ out,
       unsigned short* __restrict__ xT, float* __restrict__ hsum,
       float* __restrict__ acc_loss) {
    __shared__ float tile[64 * 257];     // [c][n_local], 257-pad
    __shared__ float hist[512];
    __shared__ float lred[4];
    const int tid = threadIdx.x;
    hist[tid] = 0.f; hist[tid + 256] = 0.f;
    __syncthreads();
    const int n  = blockIdx.x * 256 + tid;
    const int bb = n >> 12, h = (n >> 6) & 63;
    const long gx = (long)bb * 262144 + (long)h * 64 + (n & 63);
    unsigned pk = bkp[n];
    int k1 = (int)(pk & 0xffffu), k2 = (int)(pk >> 16);
    if (k2 != k1) {   // exact fp32 re-decision; rare
        const float4* e1 = (const float4*)(cbg + (k1 << 6));
        const float4* e2 = (const float4*)(cbg + (k2 << 6));
        float a0 = 0.f, a1 = 0.f, c0 = 0.f, c1 = 0.f;
        #pragma unroll 4
        for (int j = 0; j < 16; ++j) {
            float4 ea = e1[j], eb = e2[j];
            float x0 = x[gx + (long)(4 * j + 0) * 4096];
            float x1 = x[gx + (long)(4 * j + 1) * 4096];
            float x2 = x[gx + (long)(4 * j + 2) * 4096];
            float x3 = x[gx + (long)(4 * j + 3) * 4096];
            a0 = fmaf(x0, ea.x, a0); a1 = fmaf(x1, ea.y, a1);
            a0 = fmaf(x2, ea.z, a0); a1 = fmaf(x3, ea.w, a1);
            c0 = fmaf(x0, eb.x, c0); c1 = fmaf(x1, eb.y, c1);
            c0 = fmaf(x2, eb.z, c0); c1 = fmaf(x3, eb.w, c1);
        }
        float s1 = esqg[k1] - 2.f * (a0 + a1);
        float s2 = esqg[k2] - 2.f * (c0 + c1);
        if (s2 < s1 || (s2 == s1 && k2 < k1)) k1 = k2;
    }
    bkg[n] = (unsigned short)k1;
    atomicAdd(&hist[k1], 1.0f);
    const float4* q4 = (const float4*)(cbg + (k1 << 6));
    float lsum = 0.f;
    #pragma unroll
    for (int j = 0; j < 16; ++j) {
        float4 q = q4[j];
        const float qv[4] = {q.x, q.y, q.z, q.w};
        #pragma unroll
        for (int r = 0; r < 4; ++r) {
            const int c = 4 * j + r;
            float xc = x[gx + (long)c * 4096];
            out[gx + (long)c * 4096] = qv[r];       // == x+(q-x) to 1 ulp (R5-proven)
            tile[c * 257 + tid] = xc;
            float d = xc - qv[r];
            lsum = fmaf(d, d, lsum);
        }
    }
    #pragma unroll
    for (int o = 32; o > 0; o >>= 1) lsum += __shfl_down(lsum, o, 64);
    if ((tid & 63) == 0) lred[tid >> 6] = lsum;
    __syncthreads();
    if (tid == 0) atomicAdd(acc_loss, (lred[0] + lred[1]) + (lred[2] + lred[3]));
    { float v = hist[tid];       if (v != 0.f) atomicAdd(&hsum[tid], v); }
    { float v = hist[tid + 256]; if (v != 0.f) atomicAdd(&hsum[tid + 256], v); }
    // ---- xT write: 256 rows x 64 c, bf16, fully coalesced (1KB/wave-instr) ----
    {
        const long base = (long)blockIdx.x * 256 * 64;
        #pragma unroll
        for (int j = 0; j < 16; ++j) {
            // flat = j*1024 + tid*4 + r ; n_l = flat>>6 ; c = flat&63
            ushort4 o4;
            const int nl = ((j * 1024 + tid * 4) >> 6);
            const int cc = (tid * 4) & 63;
            o4.x = f2bf(tile[(cc + 0) * 257 + nl]);
            o4.y = f2bf(tile[(cc + 1) * 257 + nl]);
            o4.z = f2bf(tile[(cc + 2) * 257 + nl]);
            o4.w = f2bf(tile[(cc + 3) * 257 + nl]);
            *(ushort4*)(xT + base + j * 1024 + tid * 4) = o4;
        }
    }
}

// ---- owner-wave segment sum: zero LDS atomics ----
// 64 blocks x 1024 thr (16 waves); wave w owns codes k&15==w (32 codes, VGPR acc);
// per 64-row window: stage bf16 rows to LDS (reg prefetch), ballot-filter, accumulate.
#define SEG_RANGE 2048
#define CASE_ADD(J) case J: a##J += v; break;
#define FLUSH(J) slab[((J << 4) | w) * 64 + lane] = a##J;

__global__ void __launch_bounds__(1024)
vq_segsum(const unsigned short* __restrict__ bkg, const unsigned short* __restrict__ xT,
          float* __restrict__ slabs) {
    __shared__ unsigned short xbuf[64 * 64];   // one 64-row bf16 window (8KB)
    const int tid  = threadIdx.x;
    const int lane = tid & 63;
    const int w    = tid >> 6;                 // 0..15
    const int nbase = blockIdx.x * SEG_RANGE;
    float a0=0.f,a1=0.f,a2=0.f,a3=0.f,a4=0.f,a5=0.f,a6=0.f,a7=0.f,
          a8=0.f,a9=0.f,a10=0.f,a11=0.f,a12=0.f,a13=0.f,a14=0.f,a15=0.f,
          a16=0.f,a17=0.f,a18=0.f,a19=0.f,a20=0.f,a21=0.f,a22=0.f,a23=0.f,
          a24=0.f,a25=0.f,a26=0.f,a27=0.f,a28=0.f,a29=0.f,a30=0.f,a31=0.f;

    ushort4 vnext = *(const ushort4*)(xT + (long)nbase * 64 + tid * 4);
    #pragma unroll 1
    for (int wnd = 0; wnd < SEG_RANGE / 64; ++wnd) {
        __syncthreads();                       // prior window reads done
        *(ushort4*)(xbuf + tid * 4) = vnext;
        __syncthreads();                       // window visible
        if (wnd + 1 < SEG_RANGE / 64)
            vnext = *(const ushort4*)(xT + (long)(nbase + (wnd + 1) * 64) * 64 + tid * 4);
        int k = bkg[nbase + wnd * 64 + lane];
        unsigned long long m = __ballot((k & 15) == w);
        while (m) {
            int b = __ffsll(m) - 1;
            m &= m - 1;
            int kk = __shfl(k, b, 64);
            float v = bf2f(xbuf[b * 64 + lane]);
            int sl = kk >> 4;                  // wave-uniform -> scalar branch tree
            switch (sl) {
                CASE_ADD(0)  CASE_ADD(1)  CASE_ADD(2)  CASE_ADD(3)
                CASE_ADD(4)  CASE_ADD(5)  CASE_ADD(6)  CASE_ADD(7)
                CASE_ADD(8)  CASE_ADD(9)  CASE_ADD(10) CASE_ADD(11)
                CASE_ADD(12) CASE_ADD(13) CASE_ADD(14) CASE_ADD(15)
                CASE_ADD(16) CASE_ADD(17) CASE_ADD(18) CASE_ADD(19)
                CASE_ADD(20) CASE_ADD(21) CASE_ADD(22) CASE_ADD(23)
                CASE_ADD(24) CASE_ADD(25) CASE_ADD(26) CASE_ADD(27)
                CASE_ADD(28) CASE_ADD(29) CASE_ADD(30) CASE_ADD(31)
            }
        }
    }
    // flush: wave w owns codes (sl<<4)|w
    float* slab = slabs + (long)blockIdx.x * 32768;
    FLUSH(0)  FLUSH(1)  FLUSH(2)  FLUSH(3)  FLUSH(4)  FLUSH(5)  FLUSH(6)  FLUSH(7)
    FLUSH(8)  FLUSH(9)  FLUSH(10) FLUSH(11) FLUSH(12) FLUSH(13) FLUSH(14) FLUSH(15)
    FLUSH(16) FLUSH(17) FLUSH(18) FLUSH(19) FLUSH(20) FLUSH(21) FLUSH(22) FLUSH(23)
    FLUSH(24) FLUSH(25) FLUSH(26) FLUSH(27) FLUSH(28) FLUSH(29) FLUSH(30) FLUSH(31)
}

__global__ void __launch_bounds__(512)
vq_scalars(const float* __restrict__ hsum, const float* __restrict__ acc_loss,
           const float* __restrict__ ema_cs, float* __restrict__ smoothed,
           float* __restrict__ out_scalars) {
    __shared__ float s_red[17];
    const int tid = threadIdx.x;
    float cnt = hsum[tid];
    float ncs = 0.99f * ema_cs[tid] + 0.01f * cnt;
    float v1 = ncs;
    float v2 = (cnt > 0.f) ? 1.f : 0.f;
    #pragma unroll
    for (int o = 32; o > 0; o >>= 1) {
        v1 += __shfl_down(v1, o, 64);
        v2 += __shfl_down(v2, o, 64);
    }
    const int wv = tid >> 6;
    if ((tid & 63) == 0) { s_red[wv] = v1; s_red[wv + 8] = v2; }
    __syncthreads();
    if (tid == 0) {
        float nn = 0.f, uq = 0.f;
        #pragma unroll
        for (int i = 0; i < 8; ++i) { nn += s_red[i]; uq += s_red[i + 8]; }
        s_red[16] = nn;
        out_scalars[0] = acc_loss[0] / 8388608.f;
        out_scalars[1] = uq;
    }
    __syncthreads();
    float nn = s_red[16];
    smoothed[tid] = (ncs + 1e-5f) / (nn + 512.f * 1e-5f) * nn;
}

__global__ void __launch_bounds__(128)
vq_codebook(const float* __restrict__ slabs, const float* __restrict__ ema_w,
            const float* __restrict__ smoothed, float* __restrict__ out_cb) {
    const int e = blockIdx.x * 128 + threadIdx.x;      // e = k*64 + c
    float s = 0.f;
    #pragma unroll 8
    for (int b = 0; b < 64; ++b) s += slabs[(long)b * 32768 + e];
    float nw = 0.99f * ema_w[e] + 0.01f * s;
    out_cb[e] = nw / smoothed[e >> 6];
}

extern "C" void kernel_launch(void* const* d_in, const int* in_sizes, int n_in,
                              void* d_out, int out_size, void* d_ws, size_t ws_size,
                              hipStream_t stream) {
    const float* x      = (const float*)d_in[0];
    const float* cb     = (const float*)d_in[1];
    const float* ema_cs = (const float*)d_in[2];
    const float* ema_w  = (const float*)d_in[3];

    float* out     = (float*)d_out;
    float* scalars = out + 8388608;
    float* out_cb  = out + 8388610;
    float* ws      = (float*)d_ws;

    // ws layout (floats):
    float* slabs    = ws;                               // 64*32768 = 2,097,152
    float* hsum     = slabs + 2097152;                  // 512
    float* acc_loss = hsum + 512;                       // 16
    float* smoothed = acc_loss + 16;                    // 512
    float* esq      = smoothed + 512;                   // 512
    char*  cbF      = (char*)(esq + 512);               // 131072 B
    unsigned int*   bkp = (unsigned int*)(cbF + 131072);     // 131072 u32
    unsigned short* bkg = (unsigned short*)(bkp + 131072);   // 131072 u16
    unsigned short* xT  = bkg + 131072;                      // 131072*64 u16 (16.8MB)
    // total ~26 MB (< R4-proven ws capacity)

    hipMemsetAsync(hsum, 0, 528 * sizeof(float), stream);    // hsum + acc_loss
    vq_prep<<<8, 512, 0, stream>>>(cb, esq, cbF);
    vq_argmin<<<1024, 256, 0, stream>>>(x, cbF, esq, bkp);
    vq_out<<<512, 256, 0, stream>>>(x, cb, esq, bkp, bkg, out, xT, hsum, acc_loss);
    vq_segsum<<<64, 1024, 0, stream>>>(bkg, xT, slabs);
    vq_scalars<<<1, 512, 0, stream>>>(hsum, acc_loss, ema_cs, smoothed, scalars);
    vq_codebook<<<256, 128, 0, stream>>>(slabs, ema_w, smoothed, out_cb);
}

// Round 9
// 128.016 us; speedup vs baseline: 1.3514x; 1.3514x over previous
//
#include <hip/hip_runtime.h>

// VQ-VAE vector quantizer: B=32,C=64,H=64,W=64, K=512, DECAY=0.99, EPS=1e-5
// N = 131072 vectors, dim 64.
// R9: R8 minus the broken segsum implementation. Segsum = onehot-GEMM
// (sums[k][c] = onehot[k][n] @ x[n][c]) rebuilt clean-room with only proven
// patterns: scalar f2bf conversions, scalar ushort index reads, ext-vector
// element writes. No inline asm, no union punning in the new kernel.

typedef __attribute__((ext_vector_type(8))) short bf16x8;
typedef __attribute__((ext_vector_type(16))) float f32x16;

#define MFMA32 __builtin_amdgcn_mfma_f32_32x32x16_bf16

__device__ __forceinline__ unsigned short f2bf(float f) {
    unsigned u = __float_as_uint(f);
    return (unsigned short)((u + 0x7fffu + ((u >> 16) & 1u)) >> 16);
}
__device__ __forceinline__ float bf2f(unsigned short h) {
    return __uint_as_float(((unsigned)h) << 16);
}

// ---- prep: esq + split hi/lo fragment-major bf16 codebook ----
// unit u = cs*2+hh, c = (u>>1)*16 + (u&1)*8 + j
// cbF layout: [hi: (u*512+k)*16B for 64KB][lo: same, +64KB]
__global__ void __launch_bounds__(512)
vq_prep(const float* __restrict__ cb, float* __restrict__ esq, char* __restrict__ cbF) {
    __shared__ float tile[64 * 65];
    const int tid = threadIdx.x;
    const int k0  = blockIdx.x * 64;
    #pragma unroll
    for (int i = tid; i < 4096; i += 512)
        tile[(i >> 6) * 65 + (i & 63)] = cb[k0 * 64 + i];
    __syncthreads();
    const int u  = tid >> 6;
    const int kl = tid & 63;
    const float* row = tile + kl * 65;
    const int cbase = (u >> 1) * 16 + (u & 1) * 8;
    bf16x8 h8, l8;
    #pragma unroll
    for (int j = 0; j < 8; ++j) {
        float e = row[cbase + j];
        unsigned short hb = f2bf(e);
        float lo = e - bf2f(hb);
        h8[j] = (short)hb;
        l8[j] = (short)f2bf(lo);
    }
    const size_t idx = (size_t)(u * 512 + k0 + kl) * 16;
    *(bf16x8*)(cbF + idx)         = h8;
    *(bf16x8*)(cbF + 65536 + idx) = l8;
    if (u == 0) {
        float s = 0.f;
        #pragma unroll
        for (int c = 0; c < 64; ++c) { float v = row[c]; s = fmaf(v, v, s); }
        esq[k0 + kl] = s;
    }
}

// top-2 update; kq ascending -> strict < keeps first (numpy argmin semantics)
__device__ __forceinline__ void upd(float s, int kq, float& b1, int& q1, float& b2, int& q2) {
    bool t1 = s < b1;
    bool t2 = s < b2;
    float nb2 = t1 ? b1 : (t2 ? s : b2);
    int   nq2 = t1 ? q1 : (t2 ? kq : q2);
    b2 = nb2; q2 = nq2;
    b1 = t1 ? s : b1;
    q1 = t1 ? kq : q1;
}

// LDS: cbhi 16384 fl | cblo 16384 fl | esq 512 fl = 133,120 B
#define AM_LDS_FLOATS 33280

__global__ void __launch_bounds__(512, 1)
vq_argmin(const float* __restrict__ x, const char* __restrict__ cbF,
          const float* __restrict__ esqg, unsigned int* __restrict__ bkp) {
    extern __shared__ float lds[];
    float* esq = lds + 32768;
    const int tid  = threadIdx.x;
    const int lane = tid & 63;
    const int wv   = tid >> 6;     // 0..7
    const int l31  = lane & 31;
    const int hh   = lane >> 5;

    // ---- stage codebook fragments (hi||lo) + esq ----
    {
        const float4* src = (const float4*)cbF;
        float4* dst = (float4*)lds;
        #pragma unroll
        for (int i = tid; i < 8192; i += 512) dst[i] = src[i];
        esq[tid] = esqg[tid];
    }

    // ---- B build: 2 n-tiles per wave (-2x, hi/lo via cvt_pk) ----
    const int nb = blockIdx.x * 512 + wv * 64;
    bf16x8 B0h[4], B0l[4], B1h[4], B1l[4];
    #pragma unroll
    for (int ct = 0; ct < 2; ++ct) {
        const int n = nb + ct * 32 + l31;
        const long gx = (long)(n >> 12) * 262144 + (long)((n >> 6) & 63) * 64 + (n & 63);
        #pragma unroll
        for (int cs = 0; cs < 4; ++cs) {
            float v[8];
            #pragma unroll
            for (int j = 0; j < 8; ++j)
                v[j] = -2.f * x[gx + (long)(cs * 16 + hh * 8 + j) * 4096];
            union { unsigned u[4]; bf16x8 v8; } uh, ul;
            #pragma unroll
            for (int p = 0; p < 4; ++p) {
                unsigned hp, lp;
                asm("v_cvt_pk_bf16_f32 %0, %1, %2" : "=v"(hp) : "v"(v[2*p]), "v"(v[2*p+1]));
                float r0 = v[2*p]     - __uint_as_float(hp << 16);
                float r1 = v[2*p + 1] - __uint_as_float(hp & 0xFFFF0000u);
                asm("v_cvt_pk_bf16_f32 %0, %1, %2" : "=v"(lp) : "v"(r0), "v"(r1));
                uh.u[p] = hp; ul.u[p] = lp;
            }
            if (ct == 0) { B0h[cs] = uh.v8; B0l[cs] = ul.v8; }
            else         { B1h[cs] = uh.v8; B1l[cs] = ul.v8; }
        }
    }
    __syncthreads();

    // ---- K loop: 16 tiles x 32 codes, 2-deep A ping-pong, esq in acc-init ----
    const bf16x8* chi = (const bf16x8*)lds;
    const bf16x8* clo = (const bf16x8*)(lds + 16384);
    float b1a = 3.4e38f, b2a = 3.4e38f, b1b = 3.4e38f, b2b = 3.4e38f;
    int   q1a = 0, q2a = 0, q1b = 0, q2b = 0;
    bf16x8 Xh[4], Xl[4], Yh[4], Yl[4];

#define LOADA(Ah, Al, kt) { _Pragma("unroll") for (int cs = 0; cs < 4; ++cs) { \
        const int fi = (cs * 2 + hh) * 512 + (kt) * 32 + l31; \
        Ah[cs] = chi[fi]; Al[cs] = clo[fi]; } }

#define STEP(Ah, Al, kt) { \
        f32x16 acc0, acc1; \
        _Pragma("unroll") for (int g = 0; g < 4; ++g) { \
            float4 e4 = *(const float4*)(esq + (kt) * 32 + 8 * g + 4 * hh); \
            acc0[4*g] = e4.x; acc0[4*g+1] = e4.y; acc0[4*g+2] = e4.z; acc0[4*g+3] = e4.w; \
            acc1[4*g] = e4.x; acc1[4*g+1] = e4.y; acc1[4*g+2] = e4.z; acc1[4*g+3] = e4.w; } \
        _Pragma("unroll") for (int cs = 0; cs < 4; ++cs) { \
            acc0 = MFMA32(Ah[cs], B0h[cs], acc0, 0, 0, 0); \
            acc1 = MFMA32(Ah[cs], B1h[cs], acc1, 0, 0, 0); \
            acc0 = MFMA32(Al[cs], B0h[cs], acc0, 0, 0, 0); \
            acc1 = MFMA32(Al[cs], B1h[cs], acc1, 0, 0, 0); \
            acc0 = MFMA32(Ah[cs], B0l[cs], acc0, 0, 0, 0); \
            acc1 = MFMA32(Ah[cs], B1l[cs], acc1, 0, 0, 0); } \
        _Pragma("unroll") for (int e = 0; e < 16; ++e) { \
            int kq = (kt) * 32 + (e & 3) + 8 * (e >> 2); \
            upd(acc0[e], kq, b1a, q1a, b2a, q2a); \
            upd(acc1[e], kq, b1b, q1b, b2b, q2b); } }

    LOADA(Xh, Xl, 0)
    #pragma unroll 1
    for (int ktp = 0; ktp < 16; ktp += 2) {
        LOADA(Yh, Yl, ktp + 1)
        STEP(Xh, Xl, ktp)
        if (ktp + 2 < 16) LOADA(Xh, Xl, ktp + 2)
        STEP(Yh, Yl, ktp + 1)
    }

    // ---- merge hh halves per tile (true k = kq + 4*hh), export packed top-2 ----
#define MERGE(b1, q1, b2, q2, ct) { \
        float mb1 = b1, mb2 = b2; int mk1 = q1 + 4 * hh, mk2 = q2 + 4 * hh; \
        float ob1 = __shfl_xor(mb1, 32, 64); int ok1 = __shfl_xor(mk1, 32, 64); \
        float ob2 = __shfl_xor(mb2, 32, 64); int ok2 = __shfl_xor(mk2, 32, 64); \
        bool t = (ob1 < mb1) || (ob1 == mb1 && ok1 < mk1); \
        float w1 = t ? ob1 : mb1;  int wk1 = t ? ok1 : mk1; \
        float l1 = t ? mb1 : ob1;  int lk1 = t ? mk1 : ok1; \
        float w2c = t ? ob2 : mb2; int wk2c = t ? ok2 : mk2; \
        bool t2 = (w2c < l1) || (w2c == l1 && wk2c < lk1); \
        float w2 = t2 ? w2c : l1;  int wk2 = t2 ? wk2c : lk1; \
        if (hh == 0) { \
            unsigned k2s = (w2 - w1 < 2e-3f) ? (unsigned)wk2 : (unsigned)wk1; \
            bkp[nb + (ct) * 32 + l31] = (unsigned)wk1 | (k2s << 16); } }

    MERGE(b1a, q1a, b2a, q2a, 0)
    MERGE(b1b, q1b, b2b, q2b, 1)
#undef LOADA
#undef STEP
#undef MERGE
}

// ---- refine near-ties + out (= q, == x+(q-x) to 1 ulp) + loss + counts ----
__global__ void __launch_bounds__(256)
vq_out(const float* __restrict__ x, const float* __restrict__ cbg,
       const float* __restrict__ esqg, const unsigned int* __restrict__ bkp,
       unsigned short* __restrict__ bkg, float* __restrict__ out,
       float* __restrict__ hsum, float* __restrict__ acc_loss) {
    __shared__ float hist[512];
    __shared__ float lred[4];
    const int tid = threadIdx.x;
    hist[tid] = 0.f; hist[tid + 256] = 0.f;
    __syncthreads();
    const int n  = blockIdx.x * 256 + tid;
    const int bb = n >> 12, h = (n >> 6) & 63;
    const long gx = (long)bb * 262144 + (long)h * 64 + (n & 63);
    unsigned pk = bkp[n];
    int k1 = (int)(pk & 0xffffu), k2 = (int)(pk >> 16);
    if (k2 != k1) {   // exact fp32 re-decision; rare
        const float4* e1 = (const float4*)(cbg + (k1 << 6));
        const float4* e2 = (const float4*)(cbg + (k2 << 6));
        float a0 = 0.f, a1 = 0.f, c0 = 0.f, c1 = 0.f;
        #pragma unroll 4
        for (int j = 0; j < 16; ++j) {
            float4 ea = e1[j], eb = e2[j];
            float x0 = x[gx + (long)(4 * j + 0) * 4096];
            float x1 = x[gx + (long)(4 * j + 1) * 4096];
            float x2 = x[gx + (long)(4 * j + 2) * 4096];
            float x3 = x[gx + (long)(4 * j + 3) * 4096];
            a0 = fmaf(x0, ea.x, a0); a1 = fmaf(x1, ea.y, a1);
            a0 = fmaf(x2, ea.z, a0); a1 = fmaf(x3, ea.w, a1);
            c0 = fmaf(x0, eb.x, c0); c1 = fmaf(x1, eb.y, c1);
            c0 = fmaf(x2, eb.z, c0); c1 = fmaf(x3, eb.w, c1);
        }
        float s1 = esqg[k1] - 2.f * (a0 + a1);
        float s2 = esqg[k2] - 2.f * (c0 + c1);
        if (s2 < s1 || (s2 == s1 && k2 < k1)) k1 = k2;
    }
    bkg[n] = (unsigned short)k1;
    atomicAdd(&hist[k1], 1.0f);
    const float4* q4 = (const float4*)(cbg + (k1 << 6));
    float lsum = 0.f;
    #pragma unroll
    for (int j = 0; j < 16; ++j) {
        float4 q = q4[j];
        const float qv[4] = {q.x, q.y, q.z, q.w};
        #pragma unroll
        for (int r = 0; r < 4; ++r) {
            const int c = 4 * j + r;
            float xc = x[gx + (long)c * 4096];
            out[gx + (long)c * 4096] = qv[r];       // == x+(q-x) to 1 ulp (R5-proven)
            float d = xc - qv[r];
            lsum = fmaf(d, d, lsum);
        }
    }
    #pragma unroll
    for (int o = 32; o > 0; o >>= 1) lsum += __shfl_down(lsum, o, 64);
    if ((tid & 63) == 0) lred[tid >> 6] = lsum;
    __syncthreads();
    if (tid == 0) atomicAdd(acc_loss, (lred[0] + lred[1]) + (lred[2] + lred[3]));
    { float v = hist[tid];       if (v != 0.f) atomicAdd(&hsum[tid], v); }
    { float v = hist[tid + 256]; if (v != 0.f) atomicAdd(&hsum[tid + 256], v); }
}

// ---- segment sum as MFMA GEMM: sums[k][c] = onehot[k][n] @ x[n][c] ----
// 256 blocks x 512 thr; block owns 512 n; wave w exclusively owns code tiles
// {w, w+8}; zero atomics; clean-room: scalar f2bf, scalar ushort reads,
// ext-vector element writes only (all proven patterns).
__global__ void __launch_bounds__(512)
vq_segsum(const float* __restrict__ x, const unsigned short* __restrict__ bkg,
          float* __restrict__ slabs) {
    const int tid  = threadIdx.x;
    const int lane = tid & 63;
    const int w    = tid >> 6;      // 0..7
    const int l31  = lane & 31;
    const int hh   = lane >> 5;
    const int n0   = blockIdx.x * 512;
    const float* xpl = x + (long)(n0 >> 12) * 262144 + (n0 & 4095);
    const int t0 = w * 32 + l31;          // owned code id, tile w,   row l31
    const int t1 = (w + 8) * 32 + l31;    // owned code id, tile w+8, row l31
    f32x16 aA0 = {}, aA1 = {}, aB0 = {}, aB1 = {};

    #pragma unroll 1
    for (int b16 = 0; b16 < 32; ++b16) {
        const int nofs = b16 * 16 + hh * 8;   // this lane's 8 k-elements (n offsets)
        // B fragments: x[n0+nofs+j][c], c = l31 (Bf0) and 32+l31 (Bf1)
        bf16x8 Bf0, Bf1;
        const float* p0 = xpl + (long)l31 * 4096 + nofs;
        const float* p1 = xpl + (long)(32 + l31) * 4096 + nofs;
        #pragma unroll
        for (int j = 0; j < 8; ++j) {
            Bf0[j] = (short)f2bf(p0[j]);
            Bf1[j] = (short)f2bf(p1[j]);
        }
        // A fragments: onehot(bkg[n0+nofs+j] == t)
        bf16x8 A0, A1;
        const unsigned short* kp = bkg + n0 + nofs;
        #pragma unroll
        for (int j = 0; j < 8; ++j) {
            const int k = kp[j];
            A0[j] = (k == t0) ? (short)0x3F80 : (short)0;   // bf16 1.0
            A1[j] = (k == t1) ? (short)0x3F80 : (short)0;
        }
        aA0 = MFMA32(A0, Bf0, aA0, 0, 0, 0);
        aA1 = MFMA32(A0, Bf1, aA1, 0, 0, 0);
        aB0 = MFMA32(A1, Bf0, aB0, 0, 0, 0);
        aB1 = MFMA32(A1, Bf1, aB1, 0, 0, 0);
    }

    // flush exclusive k-rows (proven D-layout: col=lane&31, row=(e&3)+8*(e>>2)+4*hh)
    float* slab = slabs + (long)blockIdx.x * 32768;
    #pragma unroll
    for (int e = 0; e < 16; ++e) {
        const int row = (e & 3) + 8 * (e >> 2) + 4 * hh;
        slab[(w * 32 + row) * 64 + l31]            = aA0[e];
        slab[(w * 32 + row) * 64 + 32 + l31]       = aA1[e];
        slab[((w + 8) * 32 + row) * 64 + l31]      = aB0[e];
        slab[((w + 8) * 32 + row) * 64 + 32 + l31] = aB1[e];
    }
}

__global__ void __launch_bounds__(512)
vq_scalars(const float* __restrict__ hsum, const float* __restrict__ acc_loss,
           const float* __restrict__ ema_cs, float* __restrict__ smoothed,
           float* __restrict__ out_scalars) {
    __shared__ float s_red[17];
    const int tid = threadIdx.x;
    float cnt = hsum[tid];
    float ncs = 0.99f * ema_cs[tid] + 0.01f * cnt;
    float v1 = ncs;
    float v2 = (cnt > 0.f) ? 1.f : 0.f;
    #pragma unroll
    for (int o = 32; o > 0; o >>= 1) {
        v1 += __shfl_down(v1, o, 64);
        v2 += __shfl_down(v2, o, 64);
    }
    const int wv = tid >> 6;
    if ((tid & 63) == 0) { s_red[wv] = v1; s_red[wv + 8] = v2; }
    __syncthreads();
    if (tid == 0) {
        float nn = 0.f, uq = 0.f;
        #pragma unroll
        for (int i = 0; i < 8; ++i) { nn += s_red[i]; uq += s_red[i + 8]; }
        s_red[16] = nn;
        out_scalars[0] = acc_loss[0] / 8388608.f;
        out_scalars[1] = uq;
    }
    __syncthreads();
    float nn = s_red[16];
    smoothed[tid] = (ncs + 1e-5f) / (nn + 512.f * 1e-5f) * nn;
}

__global__ void __launch_bounds__(128)
vq_codebook(const float* __restrict__ slabs, const float* __restrict__ ema_w,
            const float* __restrict__ smoothed, float* __restrict__ out_cb) {
    const int e = blockIdx.x * 128 + threadIdx.x;      // e = k*64 + c
    float s = 0.f;
    #pragma unroll 8
    for (int b = 0; b < 256; ++b) s += slabs[(long)b * 32768 + e];
    float nw = 0.99f * ema_w[e] + 0.01f * s;
    out_cb[e] = nw / smoothed[e >> 6];
}

extern "C" void kernel_launch(void* const* d_in, const int* in_sizes, int n_in,
                              void* d_out, int out_size, void* d_ws, size_t ws_size,
                              hipStream_t stream) {
    const float* x      = (const float*)d_in[0];
    const float* cb     = (const float*)d_in[1];
    const float* ema_cs = (const float*)d_in[2];
    const float* ema_w  = (const float*)d_in[3];

    float* out     = (float*)d_out;
    float* scalars = out + 8388608;
    float* out_cb  = out + 8388610;
    float* ws      = (float*)d_ws;

    // ws layout (floats):
    float* slabs    = ws;                               // 256*32768 = 8,388,608 (32MB)
    float* hsum     = slabs + 8388608;                  // 512
    float* acc_loss = hsum + 512;                       // 16
    float* smoothed = acc_loss + 16;                    // 512
    float* esq      = smoothed + 512;                   // 512
    char*  cbF      = (char*)(esq + 512);               // 131072 B
    unsigned int*   bkp = (unsigned int*)(cbF + 131072);     // 131072 u32
    unsigned short* bkg = (unsigned short*)(bkp + 131072);   // 131072 u16
    // total ~34.5 MB (R4 proved >= 34.6 MB available)

    hipMemsetAsync(hsum, 0, 528 * sizeof(float), stream);    // hsum + acc_loss
    vq_prep<<<8, 512, 0, stream>>>(cb, esq, cbF);
    vq_argmin<<<256, 512, AM_LDS_FLOATS * sizeof(float), stream>>>(x, cbF, esq, bkp);
    vq_out<<<512, 256, 0, stream>>>(x, cb, esq, bkp, bkg, out, hsum, acc_loss);
    vq_segsum<<<256, 512, 0, stream>>>(x, bkg, slabs);
    vq_scalars<<<1, 512, 0, stream>>>(hsum, acc_loss, ema_cs, smoothed, scalars);
    vq_codebook<<<256, 128, 0, stream>>>(slabs, ema_w, smoothed, out_cb);
}